// Round 17
// baseline (197.475 us; speedup 1.0000x reference)
//
#include <hip/hip_runtime.h>
#include <math.h>

#define N_OUT 32
#define D_OUT 32
#define N_IN 2048
#define D_IN 16
#define BATCH 64
#define J 1024           // N_OUT*D_OUT

typedef __attribute__((ext_vector_type(8))) short short8;    // 8 bf16 (4 VGPR)
typedef __attribute__((ext_vector_type(4))) float f32x4;     // 16x16 C/D
typedef __attribute__((ext_vector_type(16))) float f32x16;   // 32x32 C/D

// f32 -> bf16 RNE
__device__ __forceinline__ unsigned short f2bf(float f) {
  unsigned int x = __float_as_uint(f);
  return (unsigned short)((x + 0x7FFFu + ((x >> 16) & 1u)) >> 16);
}

// 16B-unit swizzle inside one n-tile (2048 units): XOR bit0 with bit3
__device__ __forceinline__ int wp(int u) { return u ^ ((u >> 3) & 1); }

__device__ __forceinline__ void pack_col(const float* wc, uint4& d0, uint4& d1) {
  d0.x = (unsigned)f2bf(wc[0])  | ((unsigned)f2bf(wc[1])  << 16);
  d0.y = (unsigned)f2bf(wc[2])  | ((unsigned)f2bf(wc[3])  << 16);
  d0.z = (unsigned)f2bf(wc[4])  | ((unsigned)f2bf(wc[5])  << 16);
  d0.w = (unsigned)f2bf(wc[6])  | ((unsigned)f2bf(wc[7])  << 16);
  d1.x = (unsigned)f2bf(wc[8])  | ((unsigned)f2bf(wc[9])  << 16);
  d1.y = (unsigned)f2bf(wc[10]) | ((unsigned)f2bf(wc[11]) << 16);
  d1.z = (unsigned)f2bf(wc[12]) | ((unsigned)f2bf(wc[13]) << 16);
  d1.w = (unsigned)f2bf(wc[14]) | ((unsigned)f2bf(wc[15]) << 16);
}

__device__ __forceinline__ short8 pack_u(const float4& a4, const float4& b4) {
  short8 B;
  B[0] = (short)f2bf(a4.x); B[1] = (short)f2bf(a4.y);
  B[2] = (short)f2bf(a4.z); B[3] = (short)f2bf(a4.w);
  B[4] = (short)f2bf(b4.x); B[5] = (short)f2bf(b4.y);
  B[6] = (short)f2bf(b4.z); B[7] = (short)f2bf(b4.w);
  return B;
}

__device__ __forceinline__ f32x16 zero16() {
  f32x16 z;
  #pragma unroll
  for (int i = 0; i < 16; ++i) z[i] = 0.f;
  return z;
}

// ============ pass0s: BARRIER-FREE pass 0 (independent waves) ============
// Wave = 64-col j-slice x 32 b x 16 n. No LDS, no __syncthreads: the MFMA
// A-fragment is gathered intra-wave via __shfl from the per-lane W column.
// grid = 128 cx x 2 bh x 4 block-jg (256-thread blocks, 4 waves each).
// W f32 read exactly once (j-slices disjoint). bh==0 blocks emit Wbf;
// jg==0 waves emit ubf.
template<int NCHUNK>
__global__ __launch_bounds__(256, 4)
void pass0s_kernel(const float* __restrict__ uf, const float* __restrict__ Wf,
                   short* __restrict__ Wbf, short* __restrict__ ubf,
                   float* __restrict__ part)
{
  const int t   = threadIdx.x;
  const int l   = t & 63;
  const int wv  = t >> 6;             // wave in block 0..3
  const int bid = blockIdx.x;
  const int bjg = bid & 3;
  const int bh  = (bid >> 2) & 1;
  const int cx  = bid >> 3;           // 0..127
  const int jg  = bjg * 4 + wv;       // 0..15
  const int j0  = jg * 64;
  const int bl  = l & 31;
  const int b   = bh * 32 + bl;
  const int kh  = l >> 5;             // k-half: i = kh*8 .. kh*8+7
  const int n0  = cx * NCHUNK;
  const bool emitW = (bh == 0);
  const bool emitU = (jg == 0);

  f32x16 acc[2];
  acc[0] = zero16();
  acc[1] = zero16();

  float wcA[16], wcB[16];
  float4 uA0, uA1, uB0, uB1;

  auto load_n = [&](float (&wc)[16], float4& u0, float4& u1, int n) {
    const float* ws = Wf + (size_t)n * (D_IN * J) + j0 + l;
    #pragma unroll
    for (int i = 0; i < 16; ++i) wc[i] = ws[i * J];
    const float* up = uf + ((size_t)b * N_IN + n) * D_IN + kh * 8;
    u0 = *reinterpret_cast<const float4*>(up);
    u1 = *reinterpret_cast<const float4*>(up + 4);
  };

  auto body = [&](const float (&wc)[16], const float4& u0, const float4& u1, int n) {
    uint4 d0, d1;
    pack_col(wc, d0, d1);
    if (emitW) {
      uint4* g = reinterpret_cast<uint4*>(Wbf + (size_t)n * (D_IN * J));
      g[wp(2 * (j0 + l))] = d0;
      g[wp(2 * (j0 + l) + 1)] = d1;
    }
    short8 B = pack_u(u0, u1);
    if (emitU)
      *reinterpret_cast<short8*>(ubf + ((size_t)b * N_IN + n) * D_IN + kh * 8) = B;
    const unsigned* p0 = reinterpret_cast<const unsigned*>(&d0);
    const unsigned* p1 = reinterpret_cast<const unsigned*>(&d1);
    #pragma unroll
    for (int q = 0; q < 2; ++q) {
      int src = q * 32 + bl;
      unsigned a[4];
      #pragma unroll
      for (int e = 0; e < 4; ++e) {
        unsigned lo = (unsigned)__shfl((int)p0[e], src);
        unsigned hi = (unsigned)__shfl((int)p1[e], src);
        a[e] = kh ? hi : lo;
      }
      short8 A = *reinterpret_cast<const short8*>(a);
      acc[q] = __builtin_amdgcn_mfma_f32_32x32x16_bf16(A, B, acc[q], 0, 0, 0);
    }
  };

  load_n(wcA, uA0, uA1, n0);

  #pragma unroll
  for (int ss = 0; ss < NCHUNK; ++ss) {
    const int n = n0 + ss;
    const bool cur_is_A = ((ss & 1) == 0);
    if (ss + 1 < NCHUNK) {
      if (cur_is_A) load_n(wcB, uB0, uB1, n + 1);
      else          load_n(wcA, uA0, uA1, n + 1);
      __builtin_amdgcn_sched_barrier(0);   // keep prefetch above current pack/MFMA
    }
    if (cur_is_A) body(wcA, uA0, uA1, n);
    else          body(wcB, uB0, uB1, n);
  }

  // epilogue: part[cx][j][b]
  #pragma unroll
  for (int q = 0; q < 2; ++q) {
    #pragma unroll
    for (int r = 0; r < 16; ++r) {
      int j = j0 + q * 32 + (r & 3) + 8 * (r >> 2) + 4 * kh;
      part[((size_t)cx * J + j) * 64 + b] = acc[q][r];
    }
  }
}

// pass1w: routing pass (logits/softmax/scale) with 32x32x16, 32 b per block.
__global__ __launch_bounds__(1024, 1)
void pass1w_kernel(const short* __restrict__ Wbf, const short* __restrict__ ubf,
                   const float* __restrict__ vin, float* __restrict__ part)
{
  __shared__ uint4 Wt[2][2048];     // double-buffered (2 x 32KB)
  __shared__ float al[2][32][33];   // logits -> c, [parity][o][b_local]

  const int t  = threadIdx.x;
  const int l  = t & 63;
  const int w  = t >> 6;
  const int bid = blockIdx.x;
  const int bh = (bid >> 3) & 1;
  const int cx = (bid & 7) | ((bid >> 4) << 3);
  const int n0 = cx * 16;

  const int bl = l & 31;
  const int b  = bh * 32 + bl;
  const int kh = l >> 5;

  int aoff[2];
  #pragma unroll
  for (int q = 0; q < 2; ++q) aoff[q] = wp(2 * (w * 64 + q * 32 + bl) + kh);

  // v as packed bf16
  unsigned vb[16];
  #pragma unroll
  for (int q = 0; q < 2; ++q) {
    #pragma unroll
    for (int g = 0; g < 4; ++g) {
      int j = w * 64 + q * 32 + 8 * g + 4 * kh;
      f32x4 v4 = *reinterpret_cast<const f32x4*>(vin + (size_t)b * J + j);
      vb[q * 8 + 2 * g]     = (unsigned)f2bf(v4[0]) | ((unsigned)f2bf(v4[1]) << 16);
      vb[q * 8 + 2 * g + 1] = (unsigned)f2bf(v4[2]) | ((unsigned)f2bf(v4[3]) << 16);
    }
  }

  f32x16 acc[2];
  acc[0] = zero16();
  acc[1] = zero16();

  short8 B;
  {
    const uint4* src = reinterpret_cast<const uint4*>(Wbf + (size_t)n0 * (D_IN * J));
    Wt[0][t] = src[t];
    Wt[0][t + 1024] = src[t + 1024];
    B = *reinterpret_cast<const short8*>(ubf + ((size_t)b * N_IN + n0) * D_IN + kh * 8);
  }
  __syncthreads();

  for (int nn = 0; nn < 16; ++nn) {
    const int n = n0 + nn;
    const int cur = nn & 1, nxt = cur ^ 1, par = nn & 1;
    const bool more = (nn + 1 < 16);

    // 1. prefetch next tile + next B
    uint4 s0, s1;
    short8 Bn;
    if (more) {
      const uint4* src = reinterpret_cast<const uint4*>(Wbf + (size_t)(n + 1) * (D_IN * J));
      s0 = src[t];
      s1 = src[t + 1024];
      Bn = *reinterpret_cast<const short8*>(ubf + ((size_t)b * N_IN + n + 1) * D_IN + kh * 8);
      __builtin_amdgcn_sched_barrier(0);
    }

    // 2. uhat: two 32x32 tiles
    f32x16 C[2];
    {
      const uint4* buf = Wt[cur];
      #pragma unroll
      for (int q = 0; q < 2; ++q) {
        short8 A = *reinterpret_cast<const short8*>(&buf[aoff[q]]);
        C[q] = __builtin_amdgcn_mfma_f32_32x32x16_bf16(A, B, zero16(), 0, 0, 0);
      }
    }

    // 3. agreement a[b][o]
    #pragma unroll
    for (int q = 0; q < 2; ++q) {
      float s = 0.f;
      #pragma unroll
      for (int r = 0; r < 16; ++r) {
        unsigned u = vb[q * 8 + (r >> 1)];
        float v = (r & 1) ? __uint_as_float(u & 0xffff0000u)
                          : __uint_as_float(u << 16);
        s += C[q][r] * v;
      }
      s += __shfl_xor(s, 32);
      if (l < 32) al[par][w * 2 + q][bl] = s;
    }

    // 4. write-late staging
    if (more) {
      Wt[nxt][t] = s0;
      Wt[nxt][t + 1024] = s1;
    }

    __syncthreads();   // (B) logits staged
    {
      // softmax over o: 1024 threads = 32 b x 32 o
      int sb = t >> 5, so = t & 31;
      float x = al[par][so][sb];
      float m = x;
      #pragma unroll
      for (int k = 1; k < 32; k <<= 1) m = fmaxf(m, __shfl_xor(m, k));
      float e = __expf(x - m);
      float sm = e;
      #pragma unroll
      for (int k = 1; k < 32; k <<= 1) sm += __shfl_xor(sm, k);
      al[par][so][sb] = e / sm;
    }
    __syncthreads();   // (C) c ready
    #pragma unroll
    for (int q = 0; q < 2; ++q) {
      float c = al[par][w * 2 + q][bl];
      #pragma unroll
      for (int r = 0; r < 16; ++r) acc[q][r] += C[q][r] * c;
    }
    // no end barrier: al parity-buffered; Wt hazards separated by (B)+(C)
    B = Bn;
  }

  // epilogue: part[cx][j][b]
  #pragma unroll
  for (int q = 0; q < 2; ++q) {
    #pragma unroll
    for (int r = 0; r < 16; ++r) {
      int j = w * 64 + q * 32 + (r & 3) + 8 * (r >> 2) + 4 * kh;
      part[((size_t)cx * J + j) * 64 + b] = acc[q][r];
    }
  }
}

// ============ old 16x16 pass_kernel (ws fallback only, MODE 2) ============
template<bool HAS_V, int MODE, int NCHUNK>
__global__ __launch_bounds__(1024, 1)
void pass_kernel(const float* __restrict__ uf, const float* __restrict__ Wf,
                 short* __restrict__ Wbf, short* __restrict__ ubf,
                 const float* __restrict__ vin, float* __restrict__ part)
{
  __shared__ uint4 Wt[2][2048];
  __shared__ float al[2][32][18];

  const int t  = threadIdx.x;
  const int l  = t & 63;
  const int w  = t >> 6;
  const int bid = blockIdx.x;
  const int bq = (bid >> 3) & 3;
  const int cx = (bid & 7) | ((bid >> 5) << 3);
  const int n0 = cx * NCHUNK;

  const int bl = l & 15;
  const int b  = bq * 16 + bl;
  const int h  = l >> 4;
  const int hA = h & 1;
  const bool ld = (l < 32);

  f32x4 vf[4];
  if (HAS_V) {
    #pragma unroll
    for (int q = 0; q < 4; ++q)
      vf[q] = *reinterpret_cast<const f32x4*>(vin + (size_t)b * J + (w*4+q)*16 + h*4);
  }

  int aoff[4];
  #pragma unroll
  for (int q = 0; q < 4; ++q) aoff[q] = wp(2 * ((w*4+q) * 16 + bl) + hA);

  f32x4 acc[4];
  #pragma unroll
  for (int q = 0; q < 4; ++q) acc[q] = f32x4{0.f, 0.f, 0.f, 0.f};

  short8 Bcur = short8{0,0,0,0,0,0,0,0};
  {
    float wc[16];
    const float* wsrc = Wf + (size_t)n0 * (D_IN * J) + t;
    #pragma unroll
    for (int i = 0; i < 16; ++i) wc[i] = wsrc[i * J];
    float4 a4 = {0,0,0,0}, b4 = {0,0,0,0};
    if (ld) {
      const float* up = uf + ((size_t)b * N_IN + n0) * D_IN + hA * 8;
      a4 = *reinterpret_cast<const float4*>(up);
      b4 = *reinterpret_cast<const float4*>(up + 4);
    }
    __builtin_amdgcn_sched_barrier(0);
    uint4 d0, d1;
    pack_col(wc, d0, d1);
    Wt[0][wp(2 * t)] = d0;
    Wt[0][wp(2 * t + 1)] = d1;
    if (ld) Bcur = pack_u(a4, b4);
  }
  __syncthreads();

  for (int nn = 0; nn < NCHUNK; ++nn) {
    const int n = n0 + nn;
    const int cur = nn & 1, nxt = cur ^ 1, par = nn & 1;
    const bool more = (nn + 1 < NCHUNK);

    float wc[16];
    float4 a4 = {0,0,0,0}, b4 = {0,0,0,0};
    if (more) {
      const float* wsrc = Wf + (size_t)(n + 1) * (D_IN * J) + t;
      #pragma unroll
      for (int i = 0; i < 16; ++i) wc[i] = wsrc[i * J];
      if (ld) {
        const float* up = uf + ((size_t)b * N_IN + n + 1) * D_IN + hA * 8;
        a4 = *reinterpret_cast<const float4*>(up);
        b4 = *reinterpret_cast<const float4*>(up + 4);
      }
      __builtin_amdgcn_sched_barrier(0);
    }

    f32x4 C[4];
    const uint4* buf = Wt[cur];
    #pragma unroll
    for (int q = 0; q < 4; ++q) {
      short8 A = short8{0,0,0,0,0,0,0,0};
      if (ld) A = *reinterpret_cast<const short8*>(&buf[aoff[q]]);
      f32x4 z = f32x4{0.f, 0.f, 0.f, 0.f};
      C[q] = __builtin_amdgcn_mfma_f32_16x16x32_bf16(A, Bcur, z, 0, 0, 0);
    }

    short8 Bn = short8{0,0,0,0,0,0,0,0};
    if (more && ld) Bn = pack_u(a4, b4);

    if (HAS_V) {
      float ap[2] = {0.f, 0.f};
      #pragma unroll
      for (int q = 0; q < 4; ++q) {
        float s = C[q][0]*vf[q][0] + C[q][1]*vf[q][1] + C[q][2]*vf[q][2] + C[q][3]*vf[q][3];
        ap[q >> 1] += s;
      }
      #pragma unroll
      for (int p = 0; p < 2; ++p) {
        float s = ap[p];
        s += __shfl_xor(s, 16);
        s += __shfl_xor(s, 32);
        if (l < 16) al[par][w * 2 + p][l] = s;
      }
      if (more) {
        uint4 d0, d1;
        pack_col(wc, d0, d1);
        Wt[nxt][wp(2 * t)] = d0;
        Wt[nxt][wp(2 * t + 1)] = d1;
      }
      __syncthreads();
      if (t < 512) {
        int sb = t >> 5, so = t & 31;
        float x = al[par][so][sb];
        float m = x;
        #pragma unroll
        for (int k = 1; k < 32; k <<= 1) m = fmaxf(m, __shfl_xor(m, k));
        float e = __expf(x - m);
        float sm = e;
        #pragma unroll
        for (int k = 1; k < 32; k <<= 1) sm += __shfl_xor(sm, k);
        al[par][so][sb] = e / sm;
      }
      __syncthreads();
      #pragma unroll
      for (int q = 0; q < 4; ++q) {
        float c = al[par][(w * 4 + q) >> 1][bl];
        acc[q] += C[q] * c;
      }
    } else {
      #pragma unroll
      for (int q = 0; q < 4; ++q) acc[q] += C[q];
      if (more) {
        uint4 d0, d1;
        pack_col(wc, d0, d1);
        Wt[nxt][wp(2 * t)] = d0;
        Wt[nxt][wp(2 * t + 1)] = d1;
      }
      __syncthreads();
    }
    Bcur = Bn;
  }

  #pragma unroll
  for (int q = 0; q < 4; ++q) {
    int jbase = (w * 4 + q) * 16 + h * 4;
    #pragma unroll
    for (int r = 0; r < 4; ++r)
      part[((size_t)cx * J + jbase + r) * 64 + b] = acc[q][r];
  }
}

// Fused chunk-reduce + squash. grid = 128 (o x b-quadrant), 1024 threads.
template<int NC>
__global__ __launch_bounds__(1024)
void rsq_kernel(const float* __restrict__ part, const float* __restrict__ addv,
                float* __restrict__ out, float prescale)
{
  __shared__ float ps[2][32][17];
  __shared__ float vl[32][17];
  __shared__ float scl[16];
  const int o  = blockIdx.x >> 2;
  const int bq = blockIdx.x & 3;
  const int t  = threadIdx.x;
  {
    const int bb = t & 15;
    const int kk = (t >> 4) & 31;
    const int ch = t >> 9;
    const float* p = part + (size_t)(o * 32 + kk) * 64 + bq * 16 + bb;
    float s = 0.f;
    #pragma unroll 8
    for (int c = ch * (NC / 2); c < (ch + 1) * (NC / 2); ++c)
      s += p[(size_t)c * (J * 64)];
    ps[ch][kk][bb] = s;
  }
  __syncthreads();
  if (t < 512) {
    int kk = t >> 4, bb = t & 15;
    vl[kk][bb] = (ps[0][kk][bb] + ps[1][kk][bb]) * prescale;
  }
  __syncthreads();
  if (t < 16) {
    float n2 = 0.f;
    #pragma unroll
    for (int k = 0; k < 32; ++k) { float x = vl[k][t]; n2 += x * x; }
    scl[t] = sqrtf(n2) / (1.f + n2);
  }
  __syncthreads();
  if (t < 512) {
    int bb = t >> 5, kk = t & 31;
    int idx = (bq * 16 + bb) * J + o * 32 + kk;
    float val = scl[bb] * vl[kk][bb];
    if (addv) val += addv[idx];
    out[idx] = val;
  }
}

extern "C" void kernel_launch(void* const* d_in, const int* in_sizes, int n_in,
                              void* d_out, int out_size, void* d_ws, size_t ws_size,
                              hipStream_t stream)
{
  const float* u = (const float*)d_in[0];
  const float* W = (const float*)d_in[1];
  float* out = (float*)d_out;
  char* ws = (char*)d_ws;

  const size_t WBF_B = (size_t)N_IN * D_IN * J * 2;        // 64 MB
  const size_t UBF_B = (size_t)BATCH * N_IN * D_IN * 2;    // 4 MB
  const size_t SMALL = 2ull * BATCH * J * 4;               // v0+vs
  const size_t PART128 = (size_t)128 * J * 64 * 4;         // 33.5 MB
  const size_t PART64  = (size_t)64 * J * 64 * 4;          // 16.7 MB

  if (ws_size >= WBF_B + UBF_B + PART128 + SMALL) {
    short* Wbf = (short*)ws;
    short* ubf = (short*)(ws + WBF_B);
    float* part = (float*)(ws + WBF_B + UBF_B);
    float* v0 = part + (size_t)128 * J * 64;
    float* vs = v0 + BATCH * J;
    // r=0: barrier-free wave-parallel pass0 (emits Wbf/ubf; W f32 read 1x)
    pass0s_kernel<16><<<1024, 256, 0, stream>>>(u, W, Wbf, ubf, part);
    rsq_kernel<128><<<128, 1024, 0, stream>>>(part, nullptr, v0, 1.f / 32.f);
    // r=1,2: 32x32x16 routing passes
    pass1w_kernel<<<256, 1024, 0, stream>>>(Wbf, ubf, v0, part);
    rsq_kernel<128><<<128, 1024, 0, stream>>>(part, v0, vs, 1.f);
    pass1w_kernel<<<256, 1024, 0, stream>>>(Wbf, ubf, vs, part);
    rsq_kernel<128><<<128, 1024, 0, stream>>>(part, nullptr, out, 1.f);
  } else if (ws_size >= PART64 + SMALL) {
    float* part = (float*)ws;
    float* v0 = part + (size_t)64 * J * 64;
    float* vs = v0 + BATCH * J;
    pass_kernel<false, 2, 32><<<256, 1024, 0, stream>>>(u, W, nullptr, nullptr, nullptr, part);
    rsq_kernel<64><<<128, 1024, 0, stream>>>(part, nullptr, v0, 1.f / 32.f);
    pass_kernel<true, 2, 32><<<256, 1024, 0, stream>>>(u, W, nullptr, nullptr, v0, part);
    rsq_kernel<64><<<128, 1024, 0, stream>>>(part, v0, vs, 1.f);
    pass_kernel<true, 2, 32><<<256, 1024, 0, stream>>>(u, W, nullptr, nullptr, vs, part);
    rsq_kernel<64><<<128, 1024, 0, stream>>>(part, nullptr, out, 1.f);
  } else {
    float* part = (float*)ws;
    float* v0 = part + (size_t)16 * J * 64;
    float* vs = v0 + BATCH * J;
    pass_kernel<false, 2, 128><<<64, 1024, 0, stream>>>(u, W, nullptr, nullptr, nullptr, part);
    rsq_kernel<16><<<128, 1024, 0, stream>>>(part, nullptr, v0, 1.f / 32.f);
    pass_kernel<true, 2, 128><<<64, 1024, 0, stream>>>(u, W, nullptr, nullptr, v0, part);
    rsq_kernel<16><<<128, 1024, 0, stream>>>(part, v0, vs, 1.f);
    pass_kernel<true, 2, 128><<<64, 1024, 0, stream>>>(u, W, nullptr, nullptr, vs, part);
    rsq_kernel<16><<<128, 1024, 0, stream>>>(part, nullptr, out, 1.f);
  }
}

// Round 18
// 190.645 us; speedup vs baseline: 1.0358x; 1.0358x over previous
//
#include <hip/hip_runtime.h>
#include <math.h>

#define N_OUT 32
#define D_OUT 32
#define N_IN 2048
#define D_IN 16
#define BATCH 64
#define J 1024           // N_OUT*D_OUT

typedef __attribute__((ext_vector_type(8))) short short8;    // 8 bf16 (4 VGPR)
typedef __attribute__((ext_vector_type(4))) float f32x4;     // 16x16 C/D
typedef __attribute__((ext_vector_type(16))) float f32x16;   // 32x32 C/D

// f32 -> bf16 RNE
__device__ __forceinline__ unsigned short f2bf(float f) {
  unsigned int x = __float_as_uint(f);
  return (unsigned short)((x + 0x7FFFu + ((x >> 16) & 1u)) >> 16);
}

// 16B-unit swizzle inside one n-tile (2048 units): XOR bit0 with bit3
__device__ __forceinline__ int wp(int u) { return u ^ ((u >> 3) & 1); }

__device__ __forceinline__ void pack_col(const float* wc, uint4& d0, uint4& d1) {
  d0.x = (unsigned)f2bf(wc[0])  | ((unsigned)f2bf(wc[1])  << 16);
  d0.y = (unsigned)f2bf(wc[2])  | ((unsigned)f2bf(wc[3])  << 16);
  d0.z = (unsigned)f2bf(wc[4])  | ((unsigned)f2bf(wc[5])  << 16);
  d0.w = (unsigned)f2bf(wc[6])  | ((unsigned)f2bf(wc[7])  << 16);
  d1.x = (unsigned)f2bf(wc[8])  | ((unsigned)f2bf(wc[9])  << 16);
  d1.y = (unsigned)f2bf(wc[10]) | ((unsigned)f2bf(wc[11]) << 16);
  d1.z = (unsigned)f2bf(wc[12]) | ((unsigned)f2bf(wc[13]) << 16);
  d1.w = (unsigned)f2bf(wc[14]) | ((unsigned)f2bf(wc[15]) << 16);
}

__device__ __forceinline__ short8 pack_u(const float4& a4, const float4& b4) {
  short8 B;
  B[0] = (short)f2bf(a4.x); B[1] = (short)f2bf(a4.y);
  B[2] = (short)f2bf(a4.z); B[3] = (short)f2bf(a4.w);
  B[4] = (short)f2bf(b4.x); B[5] = (short)f2bf(b4.y);
  B[6] = (short)f2bf(b4.z); B[7] = (short)f2bf(b4.w);
  return B;
}

__device__ __forceinline__ f32x16 zero16() {
  f32x16 z;
  #pragma unroll
  for (int i = 0; i < 16; ++i) z[i] = 0.f;
  return z;
}

// ================== 32x32x16 decomposition (round-16 proven) ==================
// Block: 1024 threads = 32 b (one half) x 1024 j x 16 n. grid 256 = 2 bh x 128 cx.
// MFMA 32x32x16: K=16 == D_IN exactly. A: row=l&31, k=(l>>5)*8+e; B: col=l&31,
// same k. C/D: col=l&31, row=(r&3)+8*(r>>2)+4*(l>>5).

// pass0w: c-uniform pass + bf16 emission. Paired-n (1 barrier / 2 n), in-place acc.
template<int MODE>   // 0: emit Wbf/ubf
__global__ __launch_bounds__(1024, 1)
void pass0w_kernel(const float* __restrict__ uf, const float* __restrict__ Wf,
                   short* __restrict__ Wbf, short* __restrict__ ubf,
                   float* __restrict__ part)
{
  __shared__ uint4 Wt[4][2048];     // quad-buffered (4 x 32KB)

  const int t  = threadIdx.x;
  const int l  = t & 63;
  const int w  = t >> 6;
  const int bid = blockIdx.x;
  const int bh = (bid >> 3) & 1;                    // b half (32 b)
  const int cx = (bid & 7) | ((bid >> 4) << 3);     // chunk 0..127 (XCD-paired)
  const int n0 = cx * 16;

  const int bl = l & 31;
  const int b  = bh * 32 + bl;
  const int kh = l >> 5;            // k-half: i = kh*8 .. kh*8+7
  const bool wq = (MODE == 0) && ((t >> 9) == bh);  // Wbf writer half
  const bool uq = (MODE == 0) && (w == 0);          // ubf writer

  int aoff[2];
  #pragma unroll
  for (int q = 0; q < 2; ++q) aoff[q] = wp(2 * (w * 64 + q * 32 + bl) + kh);

  f32x16 acc[2];
  acc[0] = zero16();
  acc[1] = zero16();

  short8 Ba, Bb;

  // prologue: pair (n0, n0+1) -> Wt[0], Wt[1]
  {
    float wa[16], wb[16];
    const float* sa = Wf + (size_t)n0 * (D_IN * J) + t;
    const float* sb = Wf + (size_t)(n0 + 1) * (D_IN * J) + t;
    #pragma unroll
    for (int i = 0; i < 16; ++i) wa[i] = sa[i * J];
    #pragma unroll
    for (int i = 0; i < 16; ++i) wb[i] = sb[i * J];
    const float* upa = uf + ((size_t)b * N_IN + n0) * D_IN + kh * 8;
    float4 ua0 = *reinterpret_cast<const float4*>(upa);
    float4 ua1 = *reinterpret_cast<const float4*>(upa + 4);
    const float* upb = uf + ((size_t)b * N_IN + n0 + 1) * D_IN + kh * 8;
    float4 ub0 = *reinterpret_cast<const float4*>(upb);
    float4 ub1 = *reinterpret_cast<const float4*>(upb + 4);
    __builtin_amdgcn_sched_barrier(0);
    uint4 d0, d1;
    pack_col(wa, d0, d1);
    Wt[0][wp(2 * t)] = d0;
    Wt[0][wp(2 * t + 1)] = d1;
    if (wq) {
      uint4* g = reinterpret_cast<uint4*>(Wbf + (size_t)n0 * (D_IN * J));
      g[wp(2 * t)] = d0;
      g[wp(2 * t + 1)] = d1;
    }
    pack_col(wb, d0, d1);
    Wt[1][wp(2 * t)] = d0;
    Wt[1][wp(2 * t + 1)] = d1;
    if (wq) {
      uint4* g = reinterpret_cast<uint4*>(Wbf + (size_t)(n0 + 1) * (D_IN * J));
      g[wp(2 * t)] = d0;
      g[wp(2 * t + 1)] = d1;
    }
    Ba = pack_u(ua0, ua1);
    Bb = pack_u(ub0, ub1);
    if (uq) {
      *reinterpret_cast<short8*>(ubf + ((size_t)b * N_IN + n0) * D_IN + kh * 8) = Ba;
      *reinterpret_cast<short8*>(ubf + ((size_t)b * N_IN + n0 + 1) * D_IN + kh * 8) = Bb;
    }
  }
  __syncthreads();

  for (int ss = 0; ss < 8; ++ss) {
    const int na = n0 + 2 * ss;
    const int p = ss & 1;
    const bool more = (ss + 1 < 8);

    float wa[16], wb[16];
    float4 ua0 = {0,0,0,0}, ua1 = {0,0,0,0}, ub0 = {0,0,0,0}, ub1 = {0,0,0,0};
    if (more) {
      const float* sa = Wf + (size_t)(na + 2) * (D_IN * J) + t;
      const float* sb = Wf + (size_t)(na + 3) * (D_IN * J) + t;
      #pragma unroll
      for (int i = 0; i < 16; ++i) wa[i] = sa[i * J];
      #pragma unroll
      for (int i = 0; i < 16; ++i) wb[i] = sb[i * J];
      const float* upa = uf + ((size_t)b * N_IN + na + 2) * D_IN + kh * 8;
      ua0 = *reinterpret_cast<const float4*>(upa);
      ua1 = *reinterpret_cast<const float4*>(upa + 4);
      const float* upb = uf + ((size_t)b * N_IN + na + 3) * D_IN + kh * 8;
      ub0 = *reinterpret_cast<const float4*>(upb);
      ub1 = *reinterpret_cast<const float4*>(upb + 4);
      __builtin_amdgcn_sched_barrier(0);
    }

    // MFMA both n's, both tiles, in place
    {
      const uint4* bufA = Wt[2 * p];
      const uint4* bufB = Wt[2 * p + 1];
      #pragma unroll
      for (int q = 0; q < 2; ++q) {
        short8 A = *reinterpret_cast<const short8*>(&bufA[aoff[q]]);
        acc[q] = __builtin_amdgcn_mfma_f32_32x32x16_bf16(A, Ba, acc[q], 0, 0, 0);
      }
      #pragma unroll
      for (int q = 0; q < 2; ++q) {
        short8 A = *reinterpret_cast<const short8*>(&bufB[aoff[q]]);
        acc[q] = __builtin_amdgcn_mfma_f32_32x32x16_bf16(A, Bb, acc[q], 0, 0, 0);
      }
    }

    // write-late next pair
    short8 Bna, Bnb;
    if (more) {
      uint4 d0, d1;
      pack_col(wa, d0, d1);
      Wt[2 * (1 - p)][wp(2 * t)] = d0;
      Wt[2 * (1 - p)][wp(2 * t + 1)] = d1;
      if (wq) {
        uint4* g = reinterpret_cast<uint4*>(Wbf + (size_t)(na + 2) * (D_IN * J));
        g[wp(2 * t)] = d0;
        g[wp(2 * t + 1)] = d1;
      }
      pack_col(wb, d0, d1);
      Wt[2 * (1 - p) + 1][wp(2 * t)] = d0;
      Wt[2 * (1 - p) + 1][wp(2 * t + 1)] = d1;
      if (wq) {
        uint4* g = reinterpret_cast<uint4*>(Wbf + (size_t)(na + 3) * (D_IN * J));
        g[wp(2 * t)] = d0;
        g[wp(2 * t + 1)] = d1;
      }
      Bna = pack_u(ua0, ua1);
      Bnb = pack_u(ub0, ub1);
      if (uq) {
        *reinterpret_cast<short8*>(ubf + ((size_t)b * N_IN + na + 2) * D_IN + kh * 8) = Bna;
        *reinterpret_cast<short8*>(ubf + ((size_t)b * N_IN + na + 3) * D_IN + kh * 8) = Bnb;
      }
      Ba = Bna;
      Bb = Bnb;
    }
    __syncthreads();
  }

  // epilogue: part[cx][j][b]
  #pragma unroll
  for (int q = 0; q < 2; ++q) {
    #pragma unroll
    for (int r = 0; r < 16; ++r) {
      int j = w * 64 + q * 32 + (r & 3) + 8 * (r >> 2) + 4 * kh;
      part[((size_t)cx * J + j) * 64 + b] = acc[q][r];
    }
  }
}

// pass1w: routing pass (logits/softmax/scale) with 32x32x16, 32 b per block.
__global__ __launch_bounds__(1024, 1)
void pass1w_kernel(const short* __restrict__ Wbf, const short* __restrict__ ubf,
                   const float* __restrict__ vin, float* __restrict__ part)
{
  __shared__ uint4 Wt[2][2048];     // double-buffered (2 x 32KB)
  __shared__ float al[2][32][33];   // logits -> c, [parity][o][b_local]

  const int t  = threadIdx.x;
  const int l  = t & 63;
  const int w  = t >> 6;
  const int bid = blockIdx.x;
  const int bh = (bid >> 3) & 1;
  const int cx = (bid & 7) | ((bid >> 4) << 3);
  const int n0 = cx * 16;

  const int bl = l & 31;
  const int b  = bh * 32 + bl;
  const int kh = l >> 5;

  int aoff[2];
  #pragma unroll
  for (int q = 0; q < 2; ++q) aoff[q] = wp(2 * (w * 64 + q * 32 + bl) + kh);

  // v as packed bf16
  unsigned vb[16];
  #pragma unroll
  for (int q = 0; q < 2; ++q) {
    #pragma unroll
    for (int g = 0; g < 4; ++g) {
      int j = w * 64 + q * 32 + 8 * g + 4 * kh;
      f32x4 v4 = *reinterpret_cast<const f32x4*>(vin + (size_t)b * J + j);
      vb[q * 8 + 2 * g]     = (unsigned)f2bf(v4[0]) | ((unsigned)f2bf(v4[1]) << 16);
      vb[q * 8 + 2 * g + 1] = (unsigned)f2bf(v4[2]) | ((unsigned)f2bf(v4[3]) << 16);
    }
  }

  f32x16 acc[2];
  acc[0] = zero16();
  acc[1] = zero16();

  short8 B;
  {
    const uint4* src = reinterpret_cast<const uint4*>(Wbf + (size_t)n0 * (D_IN * J));
    Wt[0][t] = src[t];
    Wt[0][t + 1024] = src[t + 1024];
    B = *reinterpret_cast<const short8*>(ubf + ((size_t)b * N_IN + n0) * D_IN + kh * 8);
  }
  __syncthreads();

  for (int nn = 0; nn < 16; ++nn) {
    const int n = n0 + nn;
    const int cur = nn & 1, nxt = cur ^ 1, par = nn & 1;
    const bool more = (nn + 1 < 16);

    // 1. prefetch next tile + next B
    uint4 s0, s1;
    short8 Bn;
    if (more) {
      const uint4* src = reinterpret_cast<const uint4*>(Wbf + (size_t)(n + 1) * (D_IN * J));
      s0 = src[t];
      s1 = src[t + 1024];
      Bn = *reinterpret_cast<const short8*>(ubf + ((size_t)b * N_IN + n + 1) * D_IN + kh * 8);
      __builtin_amdgcn_sched_barrier(0);
    }

    // 2. uhat: two 32x32 tiles
    f32x16 C[2];
    {
      const uint4* buf = Wt[cur];
      #pragma unroll
      for (int q = 0; q < 2; ++q) {
        short8 A = *reinterpret_cast<const short8*>(&buf[aoff[q]]);
        C[q] = __builtin_amdgcn_mfma_f32_32x32x16_bf16(A, B, zero16(), 0, 0, 0);
      }
    }

    // 3. agreement a[b][o]
    #pragma unroll
    for (int q = 0; q < 2; ++q) {
      float s = 0.f;
      #pragma unroll
      for (int r = 0; r < 16; ++r) {
        unsigned u = vb[q * 8 + (r >> 1)];
        float v = (r & 1) ? __uint_as_float(u & 0xffff0000u)
                          : __uint_as_float(u << 16);
        s += C[q][r] * v;
      }
      s += __shfl_xor(s, 32);
      if (l < 32) al[par][w * 2 + q][bl] = s;
    }

    // 4. write-late staging
    if (more) {
      Wt[nxt][t] = s0;
      Wt[nxt][t + 1024] = s1;
    }

    __syncthreads();   // (B) logits staged
    {
      // softmax over o: 1024 threads = 32 b x 32 o
      int sb = t >> 5, so = t & 31;
      float x = al[par][so][sb];
      float m = x;
      #pragma unroll
      for (int k = 1; k < 32; k <<= 1) m = fmaxf(m, __shfl_xor(m, k));
      float e = __expf(x - m);
      float sm = e;
      #pragma unroll
      for (int k = 1; k < 32; k <<= 1) sm += __shfl_xor(sm, k);
      al[par][so][sb] = e / sm;
    }
    __syncthreads();   // (C) c ready
    #pragma unroll
    for (int q = 0; q < 2; ++q) {
      float c = al[par][w * 2 + q][bl];
      #pragma unroll
      for (int r = 0; r < 16; ++r) acc[q][r] += C[q][r] * c;
    }
    // no end barrier: al parity-buffered; Wt hazards separated by (B)+(C)
    B = Bn;
  }

  // epilogue: part[cx][j][b]
  #pragma unroll
  for (int q = 0; q < 2; ++q) {
    #pragma unroll
    for (int r = 0; r < 16; ++r) {
      int j = w * 64 + q * 32 + (r & 3) + 8 * (r >> 2) + 4 * kh;
      part[((size_t)cx * J + j) * 64 + b] = acc[q][r];
    }
  }
}

// ============ old 16x16 pass_kernel (ws fallback only, MODE 2) ============
template<bool HAS_V, int MODE, int NCHUNK>
__global__ __launch_bounds__(1024, 1)
void pass_kernel(const float* __restrict__ uf, const float* __restrict__ Wf,
                 short* __restrict__ Wbf, short* __restrict__ ubf,
                 const float* __restrict__ vin, float* __restrict__ part)
{
  __shared__ uint4 Wt[2][2048];
  __shared__ float al[2][32][18];

  const int t  = threadIdx.x;
  const int l  = t & 63;
  const int w  = t >> 6;
  const int bid = blockIdx.x;
  const int bq = (bid >> 3) & 3;
  const int cx = (bid & 7) | ((bid >> 5) << 3);
  const int n0 = cx * NCHUNK;

  const int bl = l & 15;
  const int b  = bq * 16 + bl;
  const int h  = l >> 4;
  const int hA = h & 1;
  const bool ld = (l < 32);

  f32x4 vf[4];
  if (HAS_V) {
    #pragma unroll
    for (int q = 0; q < 4; ++q)
      vf[q] = *reinterpret_cast<const f32x4*>(vin + (size_t)b * J + (w*4+q)*16 + h*4);
  }

  int aoff[4];
  #pragma unroll
  for (int q = 0; q < 4; ++q) aoff[q] = wp(2 * ((w*4+q) * 16 + bl) + hA);

  f32x4 acc[4];
  #pragma unroll
  for (int q = 0; q < 4; ++q) acc[q] = f32x4{0.f, 0.f, 0.f, 0.f};

  short8 Bcur = short8{0,0,0,0,0,0,0,0};
  {
    float wc[16];
    const float* wsrc = Wf + (size_t)n0 * (D_IN * J) + t;
    #pragma unroll
    for (int i = 0; i < 16; ++i) wc[i] = wsrc[i * J];
    float4 a4 = {0,0,0,0}, b4 = {0,0,0,0};
    if (ld) {
      const float* up = uf + ((size_t)b * N_IN + n0) * D_IN + hA * 8;
      a4 = *reinterpret_cast<const float4*>(up);
      b4 = *reinterpret_cast<const float4*>(up + 4);
    }
    __builtin_amdgcn_sched_barrier(0);
    uint4 d0, d1;
    pack_col(wc, d0, d1);
    Wt[0][wp(2 * t)] = d0;
    Wt[0][wp(2 * t + 1)] = d1;
    if (ld) Bcur = pack_u(a4, b4);
  }
  __syncthreads();

  for (int nn = 0; nn < NCHUNK; ++nn) {
    const int n = n0 + nn;
    const int cur = nn & 1, nxt = cur ^ 1, par = nn & 1;
    const bool more = (nn + 1 < NCHUNK);

    float wc[16];
    float4 a4 = {0,0,0,0}, b4 = {0,0,0,0};
    if (more) {
      const float* wsrc = Wf + (size_t)(n + 1) * (D_IN * J) + t;
      #pragma unroll
      for (int i = 0; i < 16; ++i) wc[i] = wsrc[i * J];
      if (ld) {
        const float* up = uf + ((size_t)b * N_IN + n + 1) * D_IN + hA * 8;
        a4 = *reinterpret_cast<const float4*>(up);
        b4 = *reinterpret_cast<const float4*>(up + 4);
      }
      __builtin_amdgcn_sched_barrier(0);
    }

    f32x4 C[4];
    const uint4* buf = Wt[cur];
    #pragma unroll
    for (int q = 0; q < 4; ++q) {
      short8 A = short8{0,0,0,0,0,0,0,0};
      if (ld) A = *reinterpret_cast<const short8*>(&buf[aoff[q]]);
      f32x4 z = f32x4{0.f, 0.f, 0.f, 0.f};
      C[q] = __builtin_amdgcn_mfma_f32_16x16x32_bf16(A, Bcur, z, 0, 0, 0);
    }

    short8 Bn = short8{0,0,0,0,0,0,0,0};
    if (more && ld) Bn = pack_u(a4, b4);

    if (HAS_V) {
      float ap[2] = {0.f, 0.f};
      #pragma unroll
      for (int q = 0; q < 4; ++q) {
        float s = C[q][0]*vf[q][0] + C[q][1]*vf[q][1] + C[q][2]*vf[q][2] + C[q][3]*vf[q][3];
        ap[q >> 1] += s;
      }
      #pragma unroll
      for (int p = 0; p < 2; ++p) {
        float s = ap[p];
        s += __shfl_xor(s, 16);
        s += __shfl_xor(s, 32);
        if (l < 16) al[par][w * 2 + p][l] = s;
      }
      if (more) {
        uint4 d0, d1;
        pack_col(wc, d0, d1);
        Wt[nxt][wp(2 * t)] = d0;
        Wt[nxt][wp(2 * t + 1)] = d1;
      }
      __syncthreads();
      if (t < 512) {
        int sb = t >> 5, so = t & 31;
        float x = al[par][so][sb];
        float m = x;
        #pragma unroll
        for (int k = 1; k < 32; k <<= 1) m = fmaxf(m, __shfl_xor(m, k));
        float e = __expf(x - m);
        float sm = e;
        #pragma unroll
        for (int k = 1; k < 32; k <<= 1) sm += __shfl_xor(sm, k);
        al[par][so][sb] = e / sm;
      }
      __syncthreads();
      #pragma unroll
      for (int q = 0; q < 4; ++q) {
        float c = al[par][(w * 4 + q) >> 1][bl];
        acc[q] += C[q] * c;
      }
    } else {
      #pragma unroll
      for (int q = 0; q < 4; ++q) acc[q] += C[q];
      if (more) {
        uint4 d0, d1;
        pack_col(wc, d0, d1);
        Wt[nxt][wp(2 * t)] = d0;
        Wt[nxt][wp(2 * t + 1)] = d1;
      }
      __syncthreads();
    }
    Bcur = Bn;
  }

  #pragma unroll
  for (int q = 0; q < 4; ++q) {
    int jbase = (w * 4 + q) * 16 + h * 4;
    #pragma unroll
    for (int r = 0; r < 4; ++r)
      part[((size_t)cx * J + jbase + r) * 64 + b] = acc[q][r];
  }
}

// Fused chunk-reduce + squash. grid = 256 (o x b-eighth of 8 b), 1024 threads.
// Doubled vs round 16's 128 blocks so all CUs are covered.
template<int NC>
__global__ __launch_bounds__(1024)
void rsq_kernel(const float* __restrict__ part, const float* __restrict__ addv,
                float* __restrict__ out, float prescale)
{
  __shared__ float ps[4][32][9];
  __shared__ float vl[32][9];
  __shared__ float scl[8];
  const int o  = blockIdx.x >> 3;       // 0..31
  const int be = blockIdx.x & 7;        // b-eighth (8 b)
  const int t  = threadIdx.x;
  {
    const int bb = t & 7;               // 0..7
    const int kk = (t >> 3) & 31;       // 0..31
    const int ch = t >> 8;              // 0..3
    const float* p = part + (size_t)(o * 32 + kk) * 64 + be * 8 + bb;
    float s = 0.f;
    #pragma unroll 8
    for (int c = ch * (NC / 4); c < (ch + 1) * (NC / 4); ++c)
      s += p[(size_t)c * (J * 64)];
    ps[ch][kk][bb] = s;
  }
  __syncthreads();
  if (t < 256) {
    int kk = t >> 3, bb = t & 7;
    vl[kk][bb] = (ps[0][kk][bb] + ps[1][kk][bb] + ps[2][kk][bb] + ps[3][kk][bb]) * prescale;
  }
  __syncthreads();
  if (t < 8) {
    float n2 = 0.f;
    #pragma unroll
    for (int k = 0; k < 32; ++k) { float x = vl[k][t]; n2 += x * x; }
    scl[t] = sqrtf(n2) / (1.f + n2);
  }
  __syncthreads();
  if (t < 256) {
    int bb = t >> 5, kk = t & 31;
    int idx = (be * 8 + bb) * J + o * 32 + kk;
    float val = scl[bb] * vl[kk][bb];
    if (addv) val += addv[idx];
    out[idx] = val;
  }
}

extern "C" void kernel_launch(void* const* d_in, const int* in_sizes, int n_in,
                              void* d_out, int out_size, void* d_ws, size_t ws_size,
                              hipStream_t stream)
{
  const float* u = (const float*)d_in[0];
  const float* W = (const float*)d_in[1];
  float* out = (float*)d_out;
  char* ws = (char*)d_ws;

  const size_t WBF_B = (size_t)N_IN * D_IN * J * 2;        // 64 MB
  const size_t UBF_B = (size_t)BATCH * N_IN * D_IN * 2;    // 4 MB
  const size_t SMALL = 2ull * BATCH * J * 4;               // v0+vs
  const size_t PART128 = (size_t)128 * J * 64 * 4;         // 33.5 MB
  const size_t PART64  = (size_t)64 * J * 64 * 4;          // 16.7 MB

  if (ws_size >= WBF_B + UBF_B + PART128 + SMALL) {
    short* Wbf = (short*)ws;
    short* ubf = (short*)(ws + WBF_B);
    float* part = (float*)(ws + WBF_B + UBF_B);
    float* v0 = part + (size_t)128 * J * 64;
    float* vs = v0 + BATCH * J;
    // r=0: 32x32x16, paired-n, emits Wbf/ubf
    pass0w_kernel<0><<<256, 1024, 0, stream>>>(u, W, Wbf, ubf, part);
    rsq_kernel<128><<<256, 1024, 0, stream>>>(part, nullptr, v0, 1.f / 32.f);
    // r=1,2: 32x32x16 routing passes
    pass1w_kernel<<<256, 1024, 0, stream>>>(Wbf, ubf, v0, part);
    rsq_kernel<128><<<256, 1024, 0, stream>>>(part, v0, vs, 1.f);
    pass1w_kernel<<<256, 1024, 0, stream>>>(Wbf, ubf, vs, part);
    rsq_kernel<128><<<256, 1024, 0, stream>>>(part, nullptr, out, 1.f);
  } else if (ws_size >= PART64 + SMALL) {
    float* part = (float*)ws;
    float* v0 = part + (size_t)64 * J * 64;
    float* vs = v0 + BATCH * J;
    pass_kernel<false, 2, 32><<<256, 1024, 0, stream>>>(u, W, nullptr, nullptr, nullptr, part);
    rsq_kernel<64><<<256, 1024, 0, stream>>>(part, nullptr, v0, 1.f / 32.f);
    pass_kernel<true, 2, 32><<<256, 1024, 0, stream>>>(u, W, nullptr, nullptr, v0, part);
    rsq_kernel<64><<<256, 1024, 0, stream>>>(part, v0, vs, 1.f);
    pass_kernel<true, 2, 32><<<256, 1024, 0, stream>>>(u, W, nullptr, nullptr, vs, part);
    rsq_kernel<64><<<256, 1024, 0, stream>>>(part, nullptr, out, 1.f);
  } else {
    float* part = (float*)ws;
    float* v0 = part + (size_t)16 * J * 64;
    float* vs = v0 + BATCH * J;
    pass_kernel<false, 2, 128><<<64, 1024, 0, stream>>>(u, W, nullptr, nullptr, nullptr, part);
    rsq_kernel<16><<<256, 1024, 0, stream>>>(part, nullptr, v0, 1.f / 32.f);
    pass_kernel<true, 2, 128><<<64, 1024, 0, stream>>>(u, W, nullptr, nullptr, v0, part);
    rsq_kernel<16><<<256, 1024, 0, stream>>>(part, v0, vs, 1.f);
    pass_kernel<true, 2, 128><<<64, 1024, 0, stream>>>(u, W, nullptr, nullptr, vs, part);
    rsq_kernel<16><<<256, 1024, 0, stream>>>(part, nullptr, out, 1.f);
  }
}

// Round 19
// 160.033 us; speedup vs baseline: 1.2340x; 1.1913x over previous
//
#include <hip/hip_runtime.h>
#include <math.h>

#define N_OUT 32
#define D_OUT 32
#define N_IN 2048
#define D_IN 16
#define BATCH 64
#define J 1024           // N_OUT*D_OUT

typedef __attribute__((ext_vector_type(8))) short short8;    // 8 bf16 (4 VGPR)
typedef __attribute__((ext_vector_type(4))) float f32x4;     // 16x16 C/D
typedef __attribute__((ext_vector_type(16))) float f32x16;   // 32x32 C/D

// f32 -> bf16 RNE
__device__ __forceinline__ unsigned short f2bf(float f) {
  unsigned int x = __float_as_uint(f);
  return (unsigned short)((x + 0x7FFFu + ((x >> 16) & 1u)) >> 16);
}

// 16B-unit swizzle inside one n-tile (2048 units): XOR bit0 with bit3
__device__ __forceinline__ int wp(int u) { return u ^ ((u >> 3) & 1); }

__device__ __forceinline__ void pack_col(const float* wc, uint4& d0, uint4& d1) {
  d0.x = (unsigned)f2bf(wc[0])  | ((unsigned)f2bf(wc[1])  << 16);
  d0.y = (unsigned)f2bf(wc[2])  | ((unsigned)f2bf(wc[3])  << 16);
  d0.z = (unsigned)f2bf(wc[4])  | ((unsigned)f2bf(wc[5])  << 16);
  d0.w = (unsigned)f2bf(wc[6])  | ((unsigned)f2bf(wc[7])  << 16);
  d1.x = (unsigned)f2bf(wc[8])  | ((unsigned)f2bf(wc[9])  << 16);
  d1.y = (unsigned)f2bf(wc[10]) | ((unsigned)f2bf(wc[11]) << 16);
  d1.z = (unsigned)f2bf(wc[12]) | ((unsigned)f2bf(wc[13]) << 16);
  d1.w = (unsigned)f2bf(wc[14]) | ((unsigned)f2bf(wc[15]) << 16);
}

__device__ __forceinline__ short8 pack_u(const float4& a4, const float4& b4) {
  short8 B;
  B[0] = (short)f2bf(a4.x); B[1] = (short)f2bf(a4.y);
  B[2] = (short)f2bf(a4.z); B[3] = (short)f2bf(a4.w);
  B[4] = (short)f2bf(b4.x); B[5] = (short)f2bf(b4.y);
  B[6] = (short)f2bf(b4.z); B[7] = (short)f2bf(b4.w);
  return B;
}

__device__ __forceinline__ f32x16 zero16() {
  f32x16 z;
  #pragma unroll
  for (int i = 0; i < 16; ++i) z[i] = 0.f;
  return z;
}

// ================== 32x32x16 decomposition (round-16 proven optimum) ==================
// Block: 1024 threads = 32 b (one half) x 1024 j x 16 n. grid 256 = 2 bh x 128 cx.
// MFMA 32x32x16: K=16 == D_IN exactly. A: row=l&31, k=(l>>5)*8+e; B: col=l&31,
// same k. C/D: col=l&31, row=(r&3)+8*(r>>2)+4*(l>>5).
// Register sweet spot: 64-j-per-wave => C[2]+acc[2]=64 regs; any n-pairing in
// pass1w needs C[4] => >128 => spill (r13 lesson). 1 block/CU is structural
// (AGPR-inclusive budget, r6/7/11/14).

// pass0w: c-uniform pass + bf16 emission. Paired-n (1 barrier / 2 n), in-place acc.
template<int MODE>   // 0: emit Wbf/ubf
__global__ __launch_bounds__(1024, 1)
void pass0w_kernel(const float* __restrict__ uf, const float* __restrict__ Wf,
                   short* __restrict__ Wbf, short* __restrict__ ubf,
                   float* __restrict__ part)
{
  __shared__ uint4 Wt[4][2048];     // quad-buffered (4 x 32KB)

  const int t  = threadIdx.x;
  const int l  = t & 63;
  const int w  = t >> 6;
  const int bid = blockIdx.x;
  const int bh = (bid >> 3) & 1;                    // b half (32 b)
  const int cx = (bid & 7) | ((bid >> 4) << 3);     // chunk 0..127 (XCD-paired)
  const int n0 = cx * 16;

  const int bl = l & 31;
  const int b  = bh * 32 + bl;
  const int kh = l >> 5;            // k-half: i = kh*8 .. kh*8+7
  const bool wq = (MODE == 0) && ((t >> 9) == bh);  // Wbf writer half
  const bool uq = (MODE == 0) && (w == 0);          // ubf writer

  int aoff[2];
  #pragma unroll
  for (int q = 0; q < 2; ++q) aoff[q] = wp(2 * (w * 64 + q * 32 + bl) + kh);

  f32x16 acc[2];
  acc[0] = zero16();
  acc[1] = zero16();

  short8 Ba, Bb;

  // prologue: pair (n0, n0+1) -> Wt[0], Wt[1]
  {
    float wa[16], wb[16];
    const float* sa = Wf + (size_t)n0 * (D_IN * J) + t;
    const float* sb = Wf + (size_t)(n0 + 1) * (D_IN * J) + t;
    #pragma unroll
    for (int i = 0; i < 16; ++i) wa[i] = sa[i * J];
    #pragma unroll
    for (int i = 0; i < 16; ++i) wb[i] = sb[i * J];
    const float* upa = uf + ((size_t)b * N_IN + n0) * D_IN + kh * 8;
    float4 ua0 = *reinterpret_cast<const float4*>(upa);
    float4 ua1 = *reinterpret_cast<const float4*>(upa + 4);
    const float* upb = uf + ((size_t)b * N_IN + n0 + 1) * D_IN + kh * 8;
    float4 ub0 = *reinterpret_cast<const float4*>(upb);
    float4 ub1 = *reinterpret_cast<const float4*>(upb + 4);
    __builtin_amdgcn_sched_barrier(0);
    uint4 d0, d1;
    pack_col(wa, d0, d1);
    Wt[0][wp(2 * t)] = d0;
    Wt[0][wp(2 * t + 1)] = d1;
    if (wq) {
      uint4* g = reinterpret_cast<uint4*>(Wbf + (size_t)n0 * (D_IN * J));
      g[wp(2 * t)] = d0;
      g[wp(2 * t + 1)] = d1;
    }
    pack_col(wb, d0, d1);
    Wt[1][wp(2 * t)] = d0;
    Wt[1][wp(2 * t + 1)] = d1;
    if (wq) {
      uint4* g = reinterpret_cast<uint4*>(Wbf + (size_t)(n0 + 1) * (D_IN * J));
      g[wp(2 * t)] = d0;
      g[wp(2 * t + 1)] = d1;
    }
    Ba = pack_u(ua0, ua1);
    Bb = pack_u(ub0, ub1);
    if (uq) {
      *reinterpret_cast<short8*>(ubf + ((size_t)b * N_IN + n0) * D_IN + kh * 8) = Ba;
      *reinterpret_cast<short8*>(ubf + ((size_t)b * N_IN + n0 + 1) * D_IN + kh * 8) = Bb;
    }
  }
  __syncthreads();

  for (int ss = 0; ss < 8; ++ss) {
    const int na = n0 + 2 * ss;
    const int p = ss & 1;
    const bool more = (ss + 1 < 8);

    float wa[16], wb[16];
    float4 ua0 = {0,0,0,0}, ua1 = {0,0,0,0}, ub0 = {0,0,0,0}, ub1 = {0,0,0,0};
    if (more) {
      const float* sa = Wf + (size_t)(na + 2) * (D_IN * J) + t;
      const float* sb = Wf + (size_t)(na + 3) * (D_IN * J) + t;
      #pragma unroll
      for (int i = 0; i < 16; ++i) wa[i] = sa[i * J];
      #pragma unroll
      for (int i = 0; i < 16; ++i) wb[i] = sb[i * J];
      const float* upa = uf + ((size_t)b * N_IN + na + 2) * D_IN + kh * 8;
      ua0 = *reinterpret_cast<const float4*>(upa);
      ua1 = *reinterpret_cast<const float4*>(upa + 4);
      const float* upb = uf + ((size_t)b * N_IN + na + 3) * D_IN + kh * 8;
      ub0 = *reinterpret_cast<const float4*>(upb);
      ub1 = *reinterpret_cast<const float4*>(upb + 4);
      __builtin_amdgcn_sched_barrier(0);
    }

    // MFMA both n's, both tiles, in place
    {
      const uint4* bufA = Wt[2 * p];
      const uint4* bufB = Wt[2 * p + 1];
      #pragma unroll
      for (int q = 0; q < 2; ++q) {
        short8 A = *reinterpret_cast<const short8*>(&bufA[aoff[q]]);
        acc[q] = __builtin_amdgcn_mfma_f32_32x32x16_bf16(A, Ba, acc[q], 0, 0, 0);
      }
      #pragma unroll
      for (int q = 0; q < 2; ++q) {
        short8 A = *reinterpret_cast<const short8*>(&bufB[aoff[q]]);
        acc[q] = __builtin_amdgcn_mfma_f32_32x32x16_bf16(A, Bb, acc[q], 0, 0, 0);
      }
    }

    // write-late next pair
    short8 Bna, Bnb;
    if (more) {
      uint4 d0, d1;
      pack_col(wa, d0, d1);
      Wt[2 * (1 - p)][wp(2 * t)] = d0;
      Wt[2 * (1 - p)][wp(2 * t + 1)] = d1;
      if (wq) {
        uint4* g = reinterpret_cast<uint4*>(Wbf + (size_t)(na + 2) * (D_IN * J));
        g[wp(2 * t)] = d0;
        g[wp(2 * t + 1)] = d1;
      }
      pack_col(wb, d0, d1);
      Wt[2 * (1 - p) + 1][wp(2 * t)] = d0;
      Wt[2 * (1 - p) + 1][wp(2 * t + 1)] = d1;
      if (wq) {
        uint4* g = reinterpret_cast<uint4*>(Wbf + (size_t)(na + 3) * (D_IN * J));
        g[wp(2 * t)] = d0;
        g[wp(2 * t + 1)] = d1;
      }
      Bna = pack_u(ua0, ua1);
      Bnb = pack_u(ub0, ub1);
      if (uq) {
        *reinterpret_cast<short8*>(ubf + ((size_t)b * N_IN + na + 2) * D_IN + kh * 8) = Bna;
        *reinterpret_cast<short8*>(ubf + ((size_t)b * N_IN + na + 3) * D_IN + kh * 8) = Bnb;
      }
      Ba = Bna;
      Bb = Bnb;
    }
    __syncthreads();
  }

  // epilogue: part[cx][j][b]
  #pragma unroll
  for (int q = 0; q < 2; ++q) {
    #pragma unroll
    for (int r = 0; r < 16; ++r) {
      int j = w * 64 + q * 32 + (r & 3) + 8 * (r >> 2) + 4 * kh;
      part[((size_t)cx * J + j) * 64 + b] = acc[q][r];
    }
  }
}

// pass1w: routing pass (logits/softmax/scale) with 32x32x16, 32 b per block.
__global__ __launch_bounds__(1024, 1)
void pass1w_kernel(const short* __restrict__ Wbf, const short* __restrict__ ubf,
                   const float* __restrict__ vin, float* __restrict__ part)
{
  __shared__ uint4 Wt[2][2048];     // double-buffered (2 x 32KB)
  __shared__ float al[2][32][33];   // logits -> c, [parity][o][b_local]

  const int t  = threadIdx.x;
  const int l  = t & 63;
  const int w  = t >> 6;
  const int bid = blockIdx.x;
  const int bh = (bid >> 3) & 1;
  const int cx = (bid & 7) | ((bid >> 4) << 3);
  const int n0 = cx * 16;

  const int bl = l & 31;
  const int b  = bh * 32 + bl;
  const int kh = l >> 5;

  int aoff[2];
  #pragma unroll
  for (int q = 0; q < 2; ++q) aoff[q] = wp(2 * (w * 64 + q * 32 + bl) + kh);

  // v as packed bf16
  unsigned vb[16];
  #pragma unroll
  for (int q = 0; q < 2; ++q) {
    #pragma unroll
    for (int g = 0; g < 4; ++g) {
      int j = w * 64 + q * 32 + 8 * g + 4 * kh;
      f32x4 v4 = *reinterpret_cast<const f32x4*>(vin + (size_t)b * J + j);
      vb[q * 8 + 2 * g]     = (unsigned)f2bf(v4[0]) | ((unsigned)f2bf(v4[1]) << 16);
      vb[q * 8 + 2 * g + 1] = (unsigned)f2bf(v4[2]) | ((unsigned)f2bf(v4[3]) << 16);
    }
  }

  f32x16 acc[2];
  acc[0] = zero16();
  acc[1] = zero16();

  short8 B;
  {
    const uint4* src = reinterpret_cast<const uint4*>(Wbf + (size_t)n0 * (D_IN * J));
    Wt[0][t] = src[t];
    Wt[0][t + 1024] = src[t + 1024];
    B = *reinterpret_cast<const short8*>(ubf + ((size_t)b * N_IN + n0) * D_IN + kh * 8);
  }
  __syncthreads();

  for (int nn = 0; nn < 16; ++nn) {
    const int n = n0 + nn;
    const int cur = nn & 1, nxt = cur ^ 1, par = nn & 1;
    const bool more = (nn + 1 < 16);

    // 1. prefetch next tile + next B
    uint4 s0, s1;
    short8 Bn;
    if (more) {
      const uint4* src = reinterpret_cast<const uint4*>(Wbf + (size_t)(n + 1) * (D_IN * J));
      s0 = src[t];
      s1 = src[t + 1024];
      Bn = *reinterpret_cast<const short8*>(ubf + ((size_t)b * N_IN + n + 1) * D_IN + kh * 8);
      __builtin_amdgcn_sched_barrier(0);
    }

    // 2. uhat: two 32x32 tiles
    f32x16 C[2];
    {
      const uint4* buf = Wt[cur];
      #pragma unroll
      for (int q = 0; q < 2; ++q) {
        short8 A = *reinterpret_cast<const short8*>(&buf[aoff[q]]);
        C[q] = __builtin_amdgcn_mfma_f32_32x32x16_bf16(A, B, zero16(), 0, 0, 0);
      }
    }

    // 3. agreement a[b][o]
    #pragma unroll
    for (int q = 0; q < 2; ++q) {
      float s = 0.f;
      #pragma unroll
      for (int r = 0; r < 16; ++r) {
        unsigned u = vb[q * 8 + (r >> 1)];
        float v = (r & 1) ? __uint_as_float(u & 0xffff0000u)
                          : __uint_as_float(u << 16);
        s += C[q][r] * v;
      }
      s += __shfl_xor(s, 32);
      if (l < 32) al[par][w * 2 + q][bl] = s;
    }

    // 4. write-late staging
    if (more) {
      Wt[nxt][t] = s0;
      Wt[nxt][t + 1024] = s1;
    }

    __syncthreads();   // (B) logits staged
    {
      // softmax over o: 1024 threads = 32 b x 32 o
      int sb = t >> 5, so = t & 31;
      float x = al[par][so][sb];
      float m = x;
      #pragma unroll
      for (int k = 1; k < 32; k <<= 1) m = fmaxf(m, __shfl_xor(m, k));
      float e = __expf(x - m);
      float sm = e;
      #pragma unroll
      for (int k = 1; k < 32; k <<= 1) sm += __shfl_xor(sm, k);
      al[par][so][sb] = e / sm;
    }
    __syncthreads();   // (C) c ready
    #pragma unroll
    for (int q = 0; q < 2; ++q) {
      float c = al[par][w * 2 + q][bl];
      #pragma unroll
      for (int r = 0; r < 16; ++r) acc[q][r] += C[q][r] * c;
    }
    // no end barrier: al parity-buffered; Wt hazards separated by (B)+(C)
    B = Bn;
  }

  // epilogue: part[cx][j][b]
  #pragma unroll
  for (int q = 0; q < 2; ++q) {
    #pragma unroll
    for (int r = 0; r < 16; ++r) {
      int j = w * 64 + q * 32 + (r & 3) + 8 * (r >> 2) + 4 * kh;
      part[((size_t)cx * J + j) * 64 + b] = acc[q][r];
    }
  }
}

// ============ old 16x16 pass_kernel (ws fallback only, MODE 2) ============
template<bool HAS_V, int MODE, int NCHUNK>
__global__ __launch_bounds__(1024, 1)
void pass_kernel(const float* __restrict__ uf, const float* __restrict__ Wf,
                 short* __restrict__ Wbf, short* __restrict__ ubf,
                 const float* __restrict__ vin, float* __restrict__ part)
{
  __shared__ uint4 Wt[2][2048];
  __shared__ float al[2][32][18];

  const int t  = threadIdx.x;
  const int l  = t & 63;
  const int w  = t >> 6;
  const int bid = blockIdx.x;
  const int bq = (bid >> 3) & 3;
  const int cx = (bid & 7) | ((bid >> 5) << 3);
  const int n0 = cx * NCHUNK;

  const int bl = l & 15;
  const int b  = bq * 16 + bl;
  const int h  = l >> 4;
  const int hA = h & 1;
  const bool ld = (l < 32);

  f32x4 vf[4];
  if (HAS_V) {
    #pragma unroll
    for (int q = 0; q < 4; ++q)
      vf[q] = *reinterpret_cast<const f32x4*>(vin + (size_t)b * J + (w*4+q)*16 + h*4);
  }

  int aoff[4];
  #pragma unroll
  for (int q = 0; q < 4; ++q) aoff[q] = wp(2 * ((w*4+q) * 16 + bl) + hA);

  f32x4 acc[4];
  #pragma unroll
  for (int q = 0; q < 4; ++q) acc[q] = f32x4{0.f, 0.f, 0.f, 0.f};

  short8 Bcur = short8{0,0,0,0,0,0,0,0};
  {
    float wc[16];
    const float* wsrc = Wf + (size_t)n0 * (D_IN * J) + t;
    #pragma unroll
    for (int i = 0; i < 16; ++i) wc[i] = wsrc[i * J];
    float4 a4 = {0,0,0,0}, b4 = {0,0,0,0};
    if (ld) {
      const float* up = uf + ((size_t)b * N_IN + n0) * D_IN + hA * 8;
      a4 = *reinterpret_cast<const float4*>(up);
      b4 = *reinterpret_cast<const float4*>(up + 4);
    }
    __builtin_amdgcn_sched_barrier(0);
    uint4 d0, d1;
    pack_col(wc, d0, d1);
    Wt[0][wp(2 * t)] = d0;
    Wt[0][wp(2 * t + 1)] = d1;
    if (ld) Bcur = pack_u(a4, b4);
  }
  __syncthreads();

  for (int nn = 0; nn < NCHUNK; ++nn) {
    const int n = n0 + nn;
    const int cur = nn & 1, nxt = cur ^ 1, par = nn & 1;
    const bool more = (nn + 1 < NCHUNK);

    float wc[16];
    float4 a4 = {0,0,0,0}, b4 = {0,0,0,0};
    if (more) {
      const float* wsrc = Wf + (size_t)(n + 1) * (D_IN * J) + t;
      #pragma unroll
      for (int i = 0; i < 16; ++i) wc[i] = wsrc[i * J];
      if (ld) {
        const float* up = uf + ((size_t)b * N_IN + n + 1) * D_IN + hA * 8;
        a4 = *reinterpret_cast<const float4*>(up);
        b4 = *reinterpret_cast<const float4*>(up + 4);
      }
      __builtin_amdgcn_sched_barrier(0);
    }

    f32x4 C[4];
    const uint4* buf = Wt[cur];
    #pragma unroll
    for (int q = 0; q < 4; ++q) {
      short8 A = short8{0,0,0,0,0,0,0,0};
      if (ld) A = *reinterpret_cast<const short8*>(&buf[aoff[q]]);
      f32x4 z = f32x4{0.f, 0.f, 0.f, 0.f};
      C[q] = __builtin_amdgcn_mfma_f32_16x16x32_bf16(A, Bcur, z, 0, 0, 0);
    }

    short8 Bn = short8{0,0,0,0,0,0,0,0};
    if (more && ld) Bn = pack_u(a4, b4);

    if (HAS_V) {
      float ap[2] = {0.f, 0.f};
      #pragma unroll
      for (int q = 0; q < 4; ++q) {
        float s = C[q][0]*vf[q][0] + C[q][1]*vf[q][1] + C[q][2]*vf[q][2] + C[q][3]*vf[q][3];
        ap[q >> 1] += s;
      }
      #pragma unroll
      for (int p = 0; p < 2; ++p) {
        float s = ap[p];
        s += __shfl_xor(s, 16);
        s += __shfl_xor(s, 32);
        if (l < 16) al[par][w * 2 + p][l] = s;
      }
      if (more) {
        uint4 d0, d1;
        pack_col(wc, d0, d1);
        Wt[nxt][wp(2 * t)] = d0;
        Wt[nxt][wp(2 * t + 1)] = d1;
      }
      __syncthreads();
      if (t < 512) {
        int sb = t >> 5, so = t & 31;
        float x = al[par][so][sb];
        float m = x;
        #pragma unroll
        for (int k = 1; k < 32; k <<= 1) m = fmaxf(m, __shfl_xor(m, k));
        float e = __expf(x - m);
        float sm = e;
        #pragma unroll
        for (int k = 1; k < 32; k <<= 1) sm += __shfl_xor(sm, k);
        al[par][so][sb] = e / sm;
      }
      __syncthreads();
      #pragma unroll
      for (int q = 0; q < 4; ++q) {
        float c = al[par][(w * 4 + q) >> 1][bl];
        acc[q] += C[q] * c;
      }
    } else {
      #pragma unroll
      for (int q = 0; q < 4; ++q) acc[q] += C[q];
      if (more) {
        uint4 d0, d1;
        pack_col(wc, d0, d1);
        Wt[nxt][wp(2 * t)] = d0;
        Wt[nxt][wp(2 * t + 1)] = d1;
      }
      __syncthreads();
    }
    Bcur = Bn;
  }

  #pragma unroll
  for (int q = 0; q < 4; ++q) {
    int jbase = (w * 4 + q) * 16 + h * 4;
    #pragma unroll
    for (int r = 0; r < 4; ++r)
      part[((size_t)cx * J + jbase + r) * 64 + b] = acc[q][r];
  }
}

// Fused chunk-reduce + squash. grid = 128 (o x b-quadrant of 16 b), 1024 threads.
// (16-b blocks are the coalescing optimum: 64B contiguous per load group — r18's
// 8-b split halved that and cost ~30 us.)
template<int NC>
__global__ __launch_bounds__(1024)
void rsq_kernel(const float* __restrict__ part, const float* __restrict__ addv,
                float* __restrict__ out, float prescale)
{
  __shared__ float ps[2][32][17];
  __shared__ float vl[32][17];
  __shared__ float scl[16];
  const int o  = blockIdx.x >> 2;
  const int bq = blockIdx.x & 3;
  const int t  = threadIdx.x;
  {
    const int bb = t & 15;
    const int kk = (t >> 4) & 31;
    const int ch = t >> 9;         // 0/1
    const float* p = part + (size_t)(o * 32 + kk) * 64 + bq * 16 + bb;
    float s = 0.f;
    #pragma unroll 8
    for (int c = ch * (NC / 2); c < (ch + 1) * (NC / 2); ++c)
      s += p[(size_t)c * (J * 64)];
    ps[ch][kk][bb] = s;
  }
  __syncthreads();
  if (t < 512) {
    int kk = t >> 4, bb = t & 15;
    vl[kk][bb] = (ps[0][kk][bb] + ps[1][kk][bb]) * prescale;
  }
  __syncthreads();
  if (t < 16) {
    float n2 = 0.f;
    #pragma unroll
    for (int k = 0; k < 32; ++k) { float x = vl[k][t]; n2 += x * x; }
    scl[t] = sqrtf(n2) / (1.f + n2);
  }
  __syncthreads();
  if (t < 512) {
    int bb = t >> 5, kk = t & 31;
    int idx = (bq * 16 + bb) * J + o * 32 + kk;
    float val = scl[bb] * vl[kk][bb];
    if (addv) val += addv[idx];
    out[idx] = val;
  }
}

extern "C" void kernel_launch(void* const* d_in, const int* in_sizes, int n_in,
                              void* d_out, int out_size, void* d_ws, size_t ws_size,
                              hipStream_t stream)
{
  const float* u = (const float*)d_in[0];
  const float* W = (const float*)d_in[1];
  float* out = (float*)d_out;
  char* ws = (char*)d_ws;

  const size_t WBF_B = (size_t)N_IN * D_IN * J * 2;        // 64 MB
  const size_t UBF_B = (size_t)BATCH * N_IN * D_IN * 2;    // 4 MB
  const size_t SMALL = 2ull * BATCH * J * 4;               // v0+vs
  const size_t PART128 = (size_t)128 * J * 64 * 4;         // 33.5 MB
  const size_t PART64  = (size_t)64 * J * 64 * 4;          // 16.7 MB

  if (ws_size >= WBF_B + UBF_B + PART128 + SMALL) {
    short* Wbf = (short*)ws;
    short* ubf = (short*)(ws + WBF_B);
    float* part = (float*)(ws + WBF_B + UBF_B);
    float* v0 = part + (size_t)128 * J * 64;
    float* vs = v0 + BATCH * J;
    // r=0: 32x32x16, paired-n, emits Wbf/ubf
    pass0w_kernel<0><<<256, 1024, 0, stream>>>(u, W, Wbf, ubf, part);
    rsq_kernel<128><<<128, 1024, 0, stream>>>(part, nullptr, v0, 1.f / 32.f);
    // r=1,2: 32x32x16 routing passes
    pass1w_kernel<<<256, 1024, 0, stream>>>(Wbf, ubf, v0, part);
    rsq_kernel<128><<<128, 1024, 0, stream>>>(part, v0, vs, 1.f);
    pass1w_kernel<<<256, 1024, 0, stream>>>(Wbf, ubf, vs, part);
    rsq_kernel<128><<<128, 1024, 0, stream>>>(part, nullptr, out, 1.f);
  } else if (ws_size >= PART64 + SMALL) {
    float* part = (float*)ws;
    float* v0 = part + (size_t)64 * J * 64;
    float* vs = v0 + BATCH * J;
    pass_kernel<false, 2, 32><<<256, 1024, 0, stream>>>(u, W, nullptr, nullptr, nullptr, part);
    rsq_kernel<64><<<128, 1024, 0, stream>>>(part, nullptr, v0, 1.f / 32.f);
    pass_kernel<true, 2, 32><<<256, 1024, 0, stream>>>(u, W, nullptr, nullptr, v0, part);
    rsq_kernel<64><<<128, 1024, 0, stream>>>(part, v0, vs, 1.f);
    pass_kernel<true, 2, 32><<<256, 1024, 0, stream>>>(u, W, nullptr, nullptr, vs, part);
    rsq_kernel<64><<<128, 1024, 0, stream>>>(part, nullptr, out, 1.f);
  } else {
    float* part = (float*)ws;
    float* v0 = part + (size_t)16 * J * 64;
    float* vs = v0 + BATCH * J;
    pass_kernel<false, 2, 128><<<64, 1024, 0, stream>>>(u, W, nullptr, nullptr, nullptr, part);
    rsq_kernel<16><<<128, 1024, 0, stream>>>(part, nullptr, v0, 1.f / 32.f);
    pass_kernel<true, 2, 128><<<64, 1024, 0, stream>>>(u, W, nullptr, nullptr, v0, part);
    rsq_kernel<16><<<128, 1024, 0, stream>>>(part, v0, vs, 1.f);
    pass_kernel<true, 2, 128><<<64, 1024, 0, stream>>>(u, W, nullptr, nullptr, vs, part);
    rsq_kernel<16><<<128, 1024, 0, stream>>>(part, nullptr, out, 1.f);
  }
}